// Round 1
// baseline (95.244 us; speedup 1.0000x reference)
//
#include <hip/hip_runtime.h>

// Per-edge dot product + bias gather:
//   out[e] = dot(h[src[e]], h[dst[e]]) + b[src[e]] + b[dst[e]]
// N_NODES=100000, N_EDGES=640000, D_FEAT=128, all fp32.
//
// One 32-lane group per edge: each lane loads float4 (16B) of each row ->
// 32 lanes * 16B = 512B = full row, fully coalesced gather. Shfl-xor reduce
// within the 32-lane segment (wave64: width arg caps the shuffle domain).

__global__ void edge_dot_kernel(const float* __restrict__ h,
                                const float* __restrict__ b,
                                const int*  __restrict__ src,
                                const int*  __restrict__ dst,
                                float* __restrict__ out,
                                int n_edges) {
    int gid  = blockIdx.x * blockDim.x + threadIdx.x;
    int edge = gid >> 5;          // 32 lanes per edge
    int lane = gid & 31;
    if (edge >= n_edges) return;

    int s = src[edge];
    int d = dst[edge];

    const float4* __restrict__ hu =
        reinterpret_cast<const float4*>(h + (long long)s * 128);
    const float4* __restrict__ hv =
        reinterpret_cast<const float4*>(h + (long long)d * 128);

    float4 u = hu[lane];
    float4 v = hv[lane];
    float p = u.x * v.x + u.y * v.y + u.z * v.z + u.w * v.w;

    // reduce across the 32-lane group
    p += __shfl_xor(p, 16, 32);
    p += __shfl_xor(p,  8, 32);
    p += __shfl_xor(p,  4, 32);
    p += __shfl_xor(p,  2, 32);
    p += __shfl_xor(p,  1, 32);

    if (lane == 0) {
        out[edge] = p + b[s] + b[d];
    }
}

extern "C" void kernel_launch(void* const* d_in, const int* in_sizes, int n_in,
                              void* d_out, int out_size, void* d_ws, size_t ws_size,
                              hipStream_t stream) {
    const float* h   = (const float*)d_in[0];
    const float* b   = (const float*)d_in[1];
    const int*   src = (const int*)d_in[2];
    const int*   dst = (const int*)d_in[3];
    float* out = (float*)d_out;

    int n_edges = in_sizes[2];                 // 640000
    int total_threads = n_edges * 32;          // 32 lanes per edge
    int block = 256;
    int grid  = (total_threads + block - 1) / block;   // 80000 blocks

    edge_dot_kernel<<<grid, block, 0, stream>>>(h, b, src, dst, out, n_edges);
}

// Round 2
// 88.997 us; speedup vs baseline: 1.0702x; 1.0702x over previous
//
#include <hip/hip_runtime.h>

// out[e] = dot(h[src[e]], h[dst[e]]) + b[src[e]] + b[dst[e]]
// N_NODES=100000, N_EDGES=640000 (divisible by 4), D_FEAT=128, fp32.
//
// R2: 4 edges per 32-lane group. Each thread issues 8 independent float4
// gathers before any dependent use -> 4x memory-level parallelism per wave
// (R1 was latency-bound: VALUBusy 30%, hbm 42% peak, occupancy 82%).
// All 4 results packed into one float4 store from lane 0.

__global__ __launch_bounds__(256)
void edge_dot_kernel(const float* __restrict__ h,
                     const float* __restrict__ b,
                     const int*  __restrict__ src,
                     const int*  __restrict__ dst,
                     float* __restrict__ out,
                     int n_edges) {
    int gid   = blockIdx.x * 256 + threadIdx.x;
    int group = gid >> 5;          // 32 lanes per group, 4 edges per group
    int lane  = gid & 31;
    int e0    = group << 2;
    if (e0 >= n_edges) return;     // n_edges % 4 == 0, so e0..e0+3 all valid

    // Edge indices (same address across the group -> broadcast loads)
    int s0 = src[e0], s1 = src[e0 + 1], s2 = src[e0 + 2], s3 = src[e0 + 3];
    int d0 = dst[e0], d1 = dst[e0 + 1], d2 = dst[e0 + 2], d3 = dst[e0 + 3];

    const float4* __restrict__ h4 = reinterpret_cast<const float4*>(h);

    // 8 independent gathers: 16B/lane x 32 lanes = full 512B row each
    float4 u0 = h4[(long long)s0 * 32 + lane];
    float4 v0 = h4[(long long)d0 * 32 + lane];
    float4 u1 = h4[(long long)s1 * 32 + lane];
    float4 v1 = h4[(long long)d1 * 32 + lane];
    float4 u2 = h4[(long long)s2 * 32 + lane];
    float4 v2 = h4[(long long)d2 * 32 + lane];
    float4 u3 = h4[(long long)s3 * 32 + lane];
    float4 v3 = h4[(long long)d3 * 32 + lane];

    // Bias (broadcast loads, issued early alongside the gathers)
    float bb0 = b[s0] + b[d0];
    float bb1 = b[s1] + b[d1];
    float bb2 = b[s2] + b[d2];
    float bb3 = b[s3] + b[d3];

    float p0 = u0.x * v0.x + u0.y * v0.y + u0.z * v0.z + u0.w * v0.w;
    float p1 = u1.x * v1.x + u1.y * v1.y + u1.z * v1.z + u1.w * v1.w;
    float p2 = u2.x * v2.x + u2.y * v2.y + u2.z * v2.z + u2.w * v2.w;
    float p3 = u3.x * v3.x + u3.y * v3.y + u3.z * v3.z + u3.w * v3.w;

    // 4 interleaved butterfly reductions across the 32-lane group
    #pragma unroll
    for (int off = 16; off >= 1; off >>= 1) {
        p0 += __shfl_xor(p0, off, 32);
        p1 += __shfl_xor(p1, off, 32);
        p2 += __shfl_xor(p2, off, 32);
        p3 += __shfl_xor(p3, off, 32);
    }

    if (lane == 0) {
        float4 r;
        r.x = p0 + bb0;
        r.y = p1 + bb1;
        r.z = p2 + bb2;
        r.w = p3 + bb3;
        *reinterpret_cast<float4*>(out + e0) = r;   // e0 % 4 == 0 -> 16B aligned
    }
}

extern "C" void kernel_launch(void* const* d_in, const int* in_sizes, int n_in,
                              void* d_out, int out_size, void* d_ws, size_t ws_size,
                              hipStream_t stream) {
    const float* h   = (const float*)d_in[0];
    const float* b   = (const float*)d_in[1];
    const int*   src = (const int*)d_in[2];
    const int*   dst = (const int*)d_in[3];
    float* out = (float*)d_out;

    int n_edges = in_sizes[2];                     // 640000
    int groups  = (n_edges + 3) / 4;               // 4 edges per 32-lane group
    long long total_threads = (long long)groups * 32;
    int block = 256;
    int grid  = (int)((total_threads + block - 1) / block);  // 20000 blocks

    edge_dot_kernel<<<grid, block, 0, stream>>>(h, b, src, dst, out, n_edges);
}

// Round 3
// 58.201 us; speedup vs baseline: 1.6365x; 1.5291x over previous
//
#include <hip/hip_runtime.h>

// out[e] = dot(h[src[e]], h[dst[e]]) + b[src[e]] + b[dst[e]]
// N_NODES=100000, N_EDGES=640000, D_FEAT=128, fp32 in/out.
//
// R3: gather throughput (bytes/lines), not latency, is the ceiling
// (R1->R2: 4x MLP gave only +7%; FETCH_SIZE pinned at ~308 MB).
// => halve gathered bytes: convert h to bf16 into d_ws (per call,
// deterministic), gather 256B rows. fp32 accumulate keeps absmax ~0.3
// vs 3.42 threshold.

// ---- bf16 convert: thread i packs 8 floats -> uint4 of 8 bf16 (RNE) ----
__device__ __forceinline__ unsigned bf16_rne(float f) {
    unsigned u = __float_as_uint(f);
    return (u + 0x7fffu + ((u >> 16) & 1u)) >> 16;
}
__device__ __forceinline__ unsigned pack2(float lo, float hi) {
    return bf16_rne(lo) | (bf16_rne(hi) << 16);
}

__global__ __launch_bounds__(256)
void cvt_bf16_kernel(const float* __restrict__ h, uint4* __restrict__ hb, int n8) {
    int i = blockIdx.x * 256 + threadIdx.x;
    if (i >= n8) return;
    const float4* h4 = reinterpret_cast<const float4*>(h);
    float4 a = h4[2 * i];
    float4 c = h4[2 * i + 1];
    uint4 r;
    r.x = pack2(a.x, a.y);
    r.y = pack2(a.z, a.w);
    r.z = pack2(c.x, c.y);
    r.w = pack2(c.z, c.w);
    hb[i] = r;
}

// ---- dot of 8 bf16 pairs held in two uint4s, fp32 accumulate ----
__device__ __forceinline__ float dot2u(unsigned u, unsigned v, float acc) {
    float ul = __uint_as_float(u << 16);
    float uh = __uint_as_float(u & 0xffff0000u);
    float vl = __uint_as_float(v << 16);
    float vh = __uint_as_float(v & 0xffff0000u);
    acc = fmaf(ul, vl, acc);
    acc = fmaf(uh, vh, acc);
    return acc;
}
__device__ __forceinline__ float dot8(uint4 u, uint4 v, float acc) {
    acc = dot2u(u.x, v.x, acc);
    acc = dot2u(u.y, v.y, acc);
    acc = dot2u(u.z, v.z, acc);
    acc = dot2u(u.w, v.w, acc);
    return acc;
}

// ---- bf16 gather-dot: 16 lanes/edge, 4 edges per 16-lane group ----
// Row = 128 bf16 = 256B = 16 uint4; lane loads uint4 (16B).
__global__ __launch_bounds__(256)
void edge_dot_bf16_kernel(const uint4* __restrict__ hb,
                          const float* __restrict__ b,
                          const int*  __restrict__ src,
                          const int*  __restrict__ dst,
                          float* __restrict__ out,
                          int n_edges) {
    int gid   = blockIdx.x * 256 + threadIdx.x;
    int group = gid >> 4;          // 16 lanes per group
    int lane  = gid & 15;
    int e0    = group << 2;        // 4 edges per group
    if (e0 >= n_edges) return;     // n_edges % 4 == 0

    int s0 = src[e0], s1 = src[e0 + 1], s2 = src[e0 + 2], s3 = src[e0 + 3];
    int d0 = dst[e0], d1 = dst[e0 + 1], d2 = dst[e0 + 2], d3 = dst[e0 + 3];

    // 8 independent 16B gathers (row stride = 16 uint4)
    uint4 u0 = hb[s0 * 16 + lane];
    uint4 v0 = hb[d0 * 16 + lane];
    uint4 u1 = hb[s1 * 16 + lane];
    uint4 v1 = hb[d1 * 16 + lane];
    uint4 u2 = hb[s2 * 16 + lane];
    uint4 v2 = hb[d2 * 16 + lane];
    uint4 u3 = hb[s3 * 16 + lane];
    uint4 v3 = hb[d3 * 16 + lane];

    float bb0 = b[s0] + b[d0];
    float bb1 = b[s1] + b[d1];
    float bb2 = b[s2] + b[d2];
    float bb3 = b[s3] + b[d3];

    float p0 = dot8(u0, v0, 0.f);
    float p1 = dot8(u1, v1, 0.f);
    float p2 = dot8(u2, v2, 0.f);
    float p3 = dot8(u3, v3, 0.f);

    // butterfly reduce across the 16-lane group
    #pragma unroll
    for (int off = 8; off >= 1; off >>= 1) {
        p0 += __shfl_xor(p0, off, 16);
        p1 += __shfl_xor(p1, off, 16);
        p2 += __shfl_xor(p2, off, 16);
        p3 += __shfl_xor(p3, off, 16);
    }

    if (lane == 0) {
        float4 r;
        r.x = p0 + bb0;
        r.y = p1 + bb1;
        r.z = p2 + bb2;
        r.w = p3 + bb3;
        *reinterpret_cast<float4*>(out + e0) = r;
    }
}

// ---- fp32 fallback (R2 kernel) if ws_size is too small ----
__global__ __launch_bounds__(256)
void edge_dot_f32_kernel(const float* __restrict__ h,
                         const float* __restrict__ b,
                         const int*  __restrict__ src,
                         const int*  __restrict__ dst,
                         float* __restrict__ out,
                         int n_edges) {
    int gid   = blockIdx.x * 256 + threadIdx.x;
    int group = gid >> 5;
    int lane  = gid & 31;
    int e0    = group << 2;
    if (e0 >= n_edges) return;

    int s0 = src[e0], s1 = src[e0 + 1], s2 = src[e0 + 2], s3 = src[e0 + 3];
    int d0 = dst[e0], d1 = dst[e0 + 1], d2 = dst[e0 + 2], d3 = dst[e0 + 3];

    const float4* __restrict__ h4 = reinterpret_cast<const float4*>(h);
    float4 u0 = h4[(long long)s0 * 32 + lane];
    float4 v0 = h4[(long long)d0 * 32 + lane];
    float4 u1 = h4[(long long)s1 * 32 + lane];
    float4 v1 = h4[(long long)d1 * 32 + lane];
    float4 u2 = h4[(long long)s2 * 32 + lane];
    float4 v2 = h4[(long long)d2 * 32 + lane];
    float4 u3 = h4[(long long)s3 * 32 + lane];
    float4 v3 = h4[(long long)d3 * 32 + lane];

    float bb0 = b[s0] + b[d0];
    float bb1 = b[s1] + b[d1];
    float bb2 = b[s2] + b[d2];
    float bb3 = b[s3] + b[d3];

    float p0 = u0.x * v0.x + u0.y * v0.y + u0.z * v0.z + u0.w * v0.w;
    float p1 = u1.x * v1.x + u1.y * v1.y + u1.z * v1.z + u1.w * v1.w;
    float p2 = u2.x * v2.x + u2.y * v2.y + u2.z * v2.z + u2.w * v2.w;
    float p3 = u3.x * v3.x + u3.y * v3.y + u3.z * v3.z + u3.w * v3.w;

    #pragma unroll
    for (int off = 16; off >= 1; off >>= 1) {
        p0 += __shfl_xor(p0, off, 32);
        p1 += __shfl_xor(p1, off, 32);
        p2 += __shfl_xor(p2, off, 32);
        p3 += __shfl_xor(p3, off, 32);
    }

    if (lane == 0) {
        float4 r;
        r.x = p0 + bb0;
        r.y = p1 + bb1;
        r.z = p2 + bb2;
        r.w = p3 + bb3;
        *reinterpret_cast<float4*>(out + e0) = r;
    }
}

extern "C" void kernel_launch(void* const* d_in, const int* in_sizes, int n_in,
                              void* d_out, int out_size, void* d_ws, size_t ws_size,
                              hipStream_t stream) {
    const float* h   = (const float*)d_in[0];
    const float* b   = (const float*)d_in[1];
    const int*   src = (const int*)d_in[2];
    const int*   dst = (const int*)d_in[3];
    float* out = (float*)d_out;

    int n_h     = in_sizes[0];                 // N_NODES * 128 = 12.8M
    int n_edges = in_sizes[2];                 // 640000

    size_t need = (size_t)n_h * 2;             // bf16 copy of h (25.6 MB)

    if (ws_size >= need) {
        // 1) convert h -> bf16 in d_ws
        uint4* hb = (uint4*)d_ws;
        int n8 = n_h / 8;                      // 1.6M threads, 8 elems each
        cvt_bf16_kernel<<<(n8 + 255) / 256, 256, 0, stream>>>(h, hb, n8);

        // 2) gather-dot on bf16 rows: 16 lanes/edge, 4 edges/group
        int groups = (n_edges + 3) / 4;
        long long total = (long long)groups * 16;
        int grid = (int)((total + 255) / 256);  // 10000 blocks
        edge_dot_bf16_kernel<<<grid, 256, 0, stream>>>(hb, b, src, dst, out, n_edges);
    } else {
        int groups = (n_edges + 3) / 4;
        long long total = (long long)groups * 32;
        int grid = (int)((total + 255) / 256);
        edge_dot_f32_kernel<<<grid, 256, 0, stream>>>(h, b, src, dst, out, n_edges);
    }
}